// Round 4
// baseline (217.014 us; speedup 1.0000x reference)
//
#include <hip/hip_runtime.h>

// Problem constants (from reference setup_inputs)
#define BB   64          // batch
#define SS   512         // seq len
#define HH   768         // hidden dim
#define WW   256         // MAX_WORD_LEN
#define WE   300         // word-embedding dim
#define OUTD (HH + WE)   // 1068
#define H4   (HH / 4)    // 192 float4/hidden row
#define O4   (OUTD / 4)  // 267 float4/out row
#define W4   (WE / 4)    // 75 float4/w2v row
#define BND  (WW + 1)    // 257 bounds per batch
#define NW   (BB * WW)   // 16384 words

// ---------------------------------------------------------------------------
// K1: bounds[b*BND+w] = lower_bound(token_ids[b,:], w); bounds[b][WW] = SS
// ---------------------------------------------------------------------------
__global__ __launch_bounds__(256)
void seg_bounds_kernel(const int* __restrict__ token_ids,
                       int* __restrict__ bounds)
{
    const int b = blockIdx.x;
    const int w = threadIdx.x;
    const int* tk = token_ids + b * SS;
    int l = 0, r = SS;
    while (l < r) { int m = (l + r) >> 1; if (tk[m] < w) l = m + 1; else r = m; }
    bounds[b * BND + w] = l;
    if (w == 0) bounds[b * BND + WW] = SS;
}

// ---------------------------------------------------------------------------
// K2: gather. One wave per word: broadcast word_id, copy 75 float4s
// (lane and lane+64). 2 independent loads in flight, then 2 stores.
// Grid: NW/4 blocks x 256.
// ---------------------------------------------------------------------------
__global__ __launch_bounds__(256)
void gather_kernel(const float* __restrict__ w2v,
                   const int*   __restrict__ word_ids,
                   float*       __restrict__ out)
{
    const int w    = blockIdx.x * 4 + (threadIdx.x >> 6);  // word 0..NW-1
    const int lane = threadIdx.x & 63;

    const int wid = word_ids[w];
    const float4* src = (const float4*)(w2v + (size_t)wid * WE);
    float4*       dst = (float4*)(out + (size_t)w * OUTD + HH);

    float4 x = src[lane];
    const bool e = lane < (W4 - 64);          // 11 tail float4s
    float4 y;
    if (e) y = src[64 + lane];
    dst[lane] = x;
    if (e) dst[64 + lane] = y;
}

// ---------------------------------------------------------------------------
// K3: segment mean, pure-stream form. One wave per (word, third-of-row):
// wave-uniform cnt -> up to 6 INDEPENDENT predicated loads (no acc chain),
// one waitcnt, pairwise-tree sum, one store. Grid: NW*3/4 blocks x 256.
// ---------------------------------------------------------------------------
__global__ __launch_bounds__(256)
void mean_kernel(const float* __restrict__ hidden,
                 const int*   __restrict__ bounds,
                 float*       __restrict__ out)
{
    const int g    = blockIdx.x * 4 + (threadIdx.x >> 6);  // wave id 0..NW*3-1
    const int lane = threadIdx.x & 63;
    const int w    = g / 3;                 // word 0..NW-1
    const int p    = g - w * 3;             // which third of the 192 float4s
    const int b    = w >> 8;
    const int wl   = w & (WW - 1);

    const int lo  = bounds[b * BND + wl];
    const int hi  = bounds[b * BND + wl + 1];
    const int cnt = hi - lo;

    const float4* hp = (const float4*)hidden
                     + (size_t)(b * SS + lo) * H4 + p * 64 + lane;

    float4 a0 = make_float4(0,0,0,0), a1 = a0, a2 = a0,
           a3 = a0, a4 = a0, a5 = a0;
    if (cnt > 0) a0 = hp[0];
    if (cnt > 1) a1 = hp[1 * H4];
    if (cnt > 2) a2 = hp[2 * H4];
    if (cnt > 3) a3 = hp[3 * H4];
    if (cnt > 4) a4 = hp[4 * H4];
    if (cnt > 5) a5 = hp[5 * H4];
    for (int s = 6; s < cnt; ++s) {         // rare (P ~ 0.3%)
        float4 v = hp[(size_t)s * H4];
        a5.x += v.x; a5.y += v.y; a5.z += v.z; a5.w += v.w;
    }

    const float inv = (cnt > 0) ? (1.0f / (float)cnt) : 0.0f;
    float4 r;
    r.x = ((a0.x + a1.x) + (a2.x + a3.x) + (a4.x + a5.x)) * inv;
    r.y = ((a0.y + a1.y) + (a2.y + a3.y) + (a4.y + a5.y)) * inv;
    r.z = ((a0.z + a1.z) + (a2.z + a3.z) + (a4.z + a5.z)) * inv;
    r.w = ((a0.w + a1.w) + (a2.w + a3.w) + (a4.w + a5.w)) * inv;

    ((float4*)out)[(size_t)w * O4 + p * 64 + lane] = r;
}

extern "C" void kernel_launch(void* const* d_in, const int* in_sizes, int n_in,
                              void* d_out, int out_size, void* d_ws, size_t ws_size,
                              hipStream_t stream) {
    const float* hidden    = (const float*)d_in[0];
    const float* w2v       = (const float*)d_in[1];
    const int*   token_ids = (const int*)d_in[2];
    const int*   word_ids  = (const int*)d_in[3];
    float*       out       = (float*)d_out;
    int*         bounds    = (int*)d_ws;   // BB*BND ints = 65.8 KB

    seg_bounds_kernel<<<BB, 256, 0, stream>>>(token_ids, bounds);
    gather_kernel<<<NW / 4, 256, 0, stream>>>(w2v, word_ids, out);
    mean_kernel<<<NW * 3 / 4, 256, 0, stream>>>(hidden, bounds, out);
}